// Round 2
// baseline (2101.917 us; speedup 1.0000x reference)
//
#include <hip/hip_runtime.h>

#define N_NODES 50000
#define N_EDGES 800000

// ---------------- degree / normalization ----------------

__global__ void k_deg_init(float* deg) {
    int i = blockIdx.x * blockDim.x + threadIdx.x;
    if (i < N_NODES) deg[i] = 1.0f;  // self-loop
}

__global__ void k_deg_accum(const int* __restrict__ dst, float* deg) {
    int e = blockIdx.x * blockDim.x + threadIdx.x;
    if (e < N_EDGES) {
        int d = dst[e];
        if (d >= 0 && d < N_NODES) unsafeAtomicAdd(&deg[d], 1.0f);
    }
}

__global__ void k_dis(float* deg) {
    int i = blockIdx.x * blockDim.x + threadIdx.x;
    if (i < N_NODES) deg[i] = 1.0f / sqrtf(deg[i]);  // deg >= 1 always
}

// ---------------- dense: H = transform(X) @ W ----------------
// MODE 0: raw input. MODE 1: input = relu(X)*scale + shift (fused BN+relu).
template<int MODE>
__global__ void k_dense(const float* __restrict__ X, const float* __restrict__ W,
                        const float* __restrict__ scale, const float* __restrict__ shift,
                        float* __restrict__ H, int FI, int FO) {
    __shared__ float xs[128];
    int node = blockIdx.x;
    for (int k = threadIdx.x; k < FI; k += blockDim.x) {
        float v = X[(size_t)node * FI + k];
        if (MODE == 1) v = fmaxf(v, 0.0f) * scale[k] + shift[k];
        xs[k] = v;
    }
    __syncthreads();
    int j = threadIdx.x;
    if (j < FO) {
        float acc = 0.0f;
        for (int k = 0; k < FI; ++k) acc = fmaf(xs[k], W[k * FO + j], acc);
        H[(size_t)node * FO + j] = acc;
    }
}

// ---------------- init A with self-loop + bias: A = H*dis^2 + b ----------------
template<int FO>
__global__ void k_init(const float* __restrict__ H, const float* __restrict__ dis,
                       const float* __restrict__ b, float* __restrict__ A) {
    int t = blockIdx.x * blockDim.x + threadIdx.x;
    if (t < N_NODES * FO) {
        int i = t / FO;
        int j = t - i * FO;
        float d = dis[i];
        A[t] = H[t] * d * d + b[j];
    }
}

// ---------------- edge scatter: A[dst] += H[src]*dis[src]*dis[dst] ----------------
template<int FO>
__global__ void k_scatter(const int* __restrict__ src, const int* __restrict__ dst,
                          const float* __restrict__ dis, const float* __restrict__ H,
                          float* __restrict__ A) {
    long long t = (long long)blockIdx.x * blockDim.x + threadIdx.x;
    if (t >= (long long)N_EDGES * FO) return;
    int e = (int)(t / FO);
    int j = (int)(t - (long long)e * FO);
    int s = src[e];
    int d = dst[e];
    if ((unsigned)s >= N_NODES || (unsigned)d >= N_NODES) return;
    float nrm = dis[s] * dis[d];
    unsafeAtomicAdd(&A[(size_t)d * FO + j], H[(size_t)s * FO + j] * nrm);
}

// ---------------- BN stats over relu(A): one block per feature ----------------
__global__ void k_bnstats(const float* __restrict__ A, const float* __restrict__ g,
                          const float* __restrict__ be, float* __restrict__ scale,
                          float* __restrict__ shift, int FO) {
    int j = blockIdx.x;
    double s = 0.0, ss = 0.0;
    for (int i = threadIdx.x; i < N_NODES; i += blockDim.x) {
        float v = fmaxf(A[(size_t)i * FO + j], 0.0f);
        s += v;
        ss += (double)v * (double)v;
    }
    __shared__ double sd[256];
    __shared__ double sq[256];
    int t = threadIdx.x;
    sd[t] = s; sq[t] = ss;
    __syncthreads();
    for (int o = 128; o > 0; o >>= 1) {
        if (t < o) { sd[t] += sd[t + o]; sq[t] += sq[t + o]; }
        __syncthreads();
    }
    if (t == 0) {
        double mu  = sd[0] / (double)N_NODES;
        double var = sq[0] / (double)N_NODES - mu * mu;
        double rstd = 1.0 / sqrt(var + 1e-5);
        float sc = (float)((double)g[j] * rstd);
        scale[j] = sc;
        shift[j] = be[j] - (float)mu * sc;
    }
}

static inline int cdiv(long long a, long long b) { return (int)((a + b - 1) / b); }

extern "C" void kernel_launch(void* const* d_in, const int* in_sizes, int n_in,
                              void* d_out, int out_size, void* d_ws, size_t ws_size,
                              hipStream_t stream) {
    const float* x = (const float*)d_in[0];
    const int* ei = (const int*)d_in[1];      // harness pushes integer inputs as int32
    const int* src = ei;                       // edge_index[0]
    const int* dst = ei + N_EDGES;             // edge_index[1]
    const float* W1 = (const float*)d_in[2];  const float* b1 = (const float*)d_in[3];
    const float* W2 = (const float*)d_in[4];  const float* b2 = (const float*)d_in[5];
    const float* W3 = (const float*)d_in[6];  const float* b3 = (const float*)d_in[7];
    const float* W4 = (const float*)d_in[8];  const float* b4 = (const float*)d_in[9];
    const float* W5 = (const float*)d_in[10]; const float* b5 = (const float*)d_in[11];
    const float* W6 = (const float*)d_in[12]; const float* b6 = (const float*)d_in[13];
    const float* g1 = (const float*)d_in[14]; const float* be1 = (const float*)d_in[15];
    const float* g2 = (const float*)d_in[16]; const float* be2 = (const float*)d_in[17];
    const float* g3 = (const float*)d_in[18]; const float* be3 = (const float*)d_in[19];
    const float* g4 = (const float*)d_in[20]; const float* be4 = (const float*)d_in[21];

    // workspace layout (~35.4 MB): dis | h | Aa | scale | shift
    float* ws = (float*)d_ws;
    float* dis   = ws;                        // N
    float* h     = dis + N_NODES;             // N*88
    float* Aa    = h + (size_t)N_NODES * 88;  // N*88
    float* scale = Aa + (size_t)N_NODES * 88; // 128
    float* shift = scale + 128;               // 128
    float* out = (float*)d_out;               // doubles as second ping-pong buffer

    const int NB = 256;

    // normalization coefficients
    k_deg_init<<<cdiv(N_NODES, NB), NB, 0, stream>>>(dis);
    k_deg_accum<<<cdiv(N_EDGES, NB), NB, 0, stream>>>(dst, dis);
    k_dis<<<cdiv(N_NODES, NB), NB, 0, stream>>>(dis);

    // L1: x[88] -> 70, relu+bn(g1), result in Aa
    k_dense<0><<<N_NODES, 128, 0, stream>>>(x, W1, nullptr, nullptr, h, 88, 70);
    k_init<70><<<cdiv((long long)N_NODES * 70, NB), NB, 0, stream>>>(h, dis, b1, Aa);
    k_scatter<70><<<cdiv((long long)N_EDGES * 70, NB), NB, 0, stream>>>(src, dst, dis, h, Aa);
    k_bnstats<<<70, 256, 0, stream>>>(Aa, g1, be1, scale, shift, 70);

    // L2: 70 -> 60, relu+bn(g2), result in out (scratch)
    k_dense<1><<<N_NODES, 128, 0, stream>>>(Aa, W2, scale, shift, h, 70, 60);
    k_init<60><<<cdiv((long long)N_NODES * 60, NB), NB, 0, stream>>>(h, dis, b2, out);
    k_scatter<60><<<cdiv((long long)N_EDGES * 60, NB), NB, 0, stream>>>(src, dst, dis, h, out);
    k_bnstats<<<60, 256, 0, stream>>>(out, g2, be2, scale, shift, 60);

    // L3: 60 -> 50, no relu/bn, result in Aa
    k_dense<1><<<N_NODES, 128, 0, stream>>>(out, W3, scale, shift, h, 60, 50);
    k_init<50><<<cdiv((long long)N_NODES * 50, NB), NB, 0, stream>>>(h, dis, b3, Aa);
    k_scatter<50><<<cdiv((long long)N_EDGES * 50, NB), NB, 0, stream>>>(src, dst, dis, h, Aa);

    // L4: 50 -> 60 (raw input), relu+bn(g3), result in out (scratch)
    k_dense<0><<<N_NODES, 128, 0, stream>>>(Aa, W4, nullptr, nullptr, h, 50, 60);
    k_init<60><<<cdiv((long long)N_NODES * 60, NB), NB, 0, stream>>>(h, dis, b4, out);
    k_scatter<60><<<cdiv((long long)N_EDGES * 60, NB), NB, 0, stream>>>(src, dst, dis, h, out);
    k_bnstats<<<60, 256, 0, stream>>>(out, g3, be3, scale, shift, 60);

    // L5: 60 -> 70, relu+bn(g4), result in Aa
    k_dense<1><<<N_NODES, 128, 0, stream>>>(out, W5, scale, shift, h, 60, 70);
    k_init<70><<<cdiv((long long)N_NODES * 70, NB), NB, 0, stream>>>(h, dis, b5, Aa);
    k_scatter<70><<<cdiv((long long)N_EDGES * 70, NB), NB, 0, stream>>>(src, dst, dis, h, Aa);
    k_bnstats<<<70, 256, 0, stream>>>(Aa, g4, be4, scale, shift, 70);

    // L6: 70 -> 88, output raw
    k_dense<1><<<N_NODES, 128, 0, stream>>>(Aa, W6, scale, shift, h, 70, 88);
    k_init<88><<<cdiv((long long)N_NODES * 88, NB), NB, 0, stream>>>(h, dis, b6, out);
    k_scatter<88><<<cdiv((long long)N_EDGES * 88, NB), NB, 0, stream>>>(src, dst, dis, h, out);
}

// Round 3
// 1189.778 us; speedup vs baseline: 1.7666x; 1.7666x over previous
//
#include <hip/hip_runtime.h>

#define NN 50000
#define NE 800000

static inline int cdiv(long long a, long long b) { return (int)((a + b - 1) / b); }

// ---------------- CSR build ----------------

__global__ void k_prep(int* __restrict__ deg, float* __restrict__ bnacc) {
    int i = blockIdx.x * blockDim.x + threadIdx.x;
    if (i < NN) deg[i] = 0;
    if (i < 768) bnacc[i] = 0.0f;
}

__global__ void k_hist(const int* __restrict__ dst, int* __restrict__ deg) {
    int e = blockIdx.x * blockDim.x + threadIdx.x;
    if (e < NE) {
        int d = dst[e];
        if ((unsigned)d < NN) atomicAdd(&deg[d], 1);
    }
}

__global__ __launch_bounds__(1024) void k_scan(const int* __restrict__ deg,
                                               int* __restrict__ row_ptr) {
    const int T = 1024;
    __shared__ int lds[T];
    int tid = threadIdx.x;
    const int chunk = (NN + T - 1) / T;  // 49
    int lo = tid * chunk;
    int hi = lo + chunk; if (hi > NN) hi = NN;
    int s = 0;
    for (int i = lo; i < hi; ++i) s += deg[i];
    lds[tid] = s;
    __syncthreads();
    int val = s;
    for (int o = 1; o < T; o <<= 1) {
        int v = (tid >= o) ? lds[tid - o] : 0;
        __syncthreads();
        lds[tid] += v;
        __syncthreads();
    }
    int run = lds[tid] - val;  // exclusive prefix
    for (int i = lo; i < hi; ++i) { row_ptr[i] = run; run += deg[i]; }
    if (tid == T - 1) row_ptr[NN] = lds[T - 1];
}

__global__ void k_dis(const int* __restrict__ deg, float* __restrict__ dis) {
    int i = blockIdx.x * blockDim.x + threadIdx.x;
    if (i < NN) dis[i] = rsqrtf((float)(deg[i] + 1));  // +1 self-loop
}

__global__ void k_cursor(const int* __restrict__ row_ptr, int* __restrict__ cursor) {
    int i = blockIdx.x * blockDim.x + threadIdx.x;
    if (i < NN) cursor[i] = row_ptr[i];
}

__global__ void k_fill(const int* __restrict__ src, const int* __restrict__ dst,
                       int* __restrict__ cursor, int* __restrict__ col) {
    int e = blockIdx.x * blockDim.x + threadIdx.x;
    if (e < NE) {
        int s = src[e], d = dst[e];
        if ((unsigned)s < NN && (unsigned)d < NN) {
            int p = atomicAdd(&cursor[d], 1);
            col[p] = s;
        }
    }
}

// ---------------- dense: H = transform(X) @ W ----------------
// MODE 0: raw input. MODE 1: input = relu(X)*scale + shift (fused BN+relu).
template<int MODE>
__global__ void k_dense(const float* __restrict__ X, const float* __restrict__ W,
                        const float* __restrict__ scale, const float* __restrict__ shift,
                        float* __restrict__ H, int FI, int FO) {
    __shared__ float xs[128];
    int node = blockIdx.x;
    for (int k = threadIdx.x; k < FI; k += blockDim.x) {
        float v = X[(size_t)node * FI + k];
        if (MODE == 1) v = fmaxf(v, 0.0f) * scale[k] + shift[k];
        xs[k] = v;
    }
    __syncthreads();
    int j = threadIdx.x;
    if (j < FO) {
        float acc = 0.0f;
        for (int k = 0; k < FI; ++k) acc = fmaf(xs[k], W[k * FO + j], acc);
        H[(size_t)node * FO + j] = acc;
    }
}

// ---------------- CSR gather: A = D^-1/2 (A+I) D^-1/2 H + b ----------------
template<int FO>
__global__ void k_gather(const float* __restrict__ h, const int* __restrict__ row_ptr,
                         const int* __restrict__ col, const float* __restrict__ dis,
                         const float* __restrict__ b, float* __restrict__ A) {
    int t = blockIdx.x * blockDim.x + threadIdx.x;
    if (t >= NN * FO) return;
    int i = t / FO;
    int j = t - i * FO;
    float di = dis[i];
    float acc = h[t] * di * di;  // self-loop
    int beg = row_ptr[i], end = row_ptr[i + 1];
    for (int k = beg; k < end; ++k) {
        int s = col[k];
        acc = fmaf(h[(size_t)s * FO + j], dis[s] * di, acc);
    }
    A[t] = acc + b[j];
}

// ---------------- BN stats over relu(A) ----------------
__global__ void k_bnpart(const float* __restrict__ A, int FO, float* __restrict__ acc) {
    __shared__ float ls[96], lq[96];
    int tid = threadIdx.x;
    if (tid < 96) { ls[tid] = 0.0f; lq[tid] = 0.0f; }
    __syncthreads();
    int total = NN * FO;
    for (int t = blockIdx.x * blockDim.x + tid; t < total; t += gridDim.x * blockDim.x) {
        float v = fmaxf(A[t], 0.0f);
        int j = t % FO;
        atomicAdd(&ls[j], v);
        atomicAdd(&lq[j], v * v);
    }
    __syncthreads();
    if (tid < FO) {
        atomicAdd(&acc[tid], ls[tid]);
        atomicAdd(&acc[96 + tid], lq[tid]);
    }
}

__global__ void k_bnfin(const float* __restrict__ acc, const float* __restrict__ g,
                        const float* __restrict__ be, float* __restrict__ scale,
                        float* __restrict__ shift, int FO) {
    int j = threadIdx.x;
    if (j < FO) {
        double mu   = (double)acc[j] / (double)NN;
        double var  = (double)acc[96 + j] / (double)NN - mu * mu;
        double rstd = 1.0 / sqrt(var + 1e-5);
        float  sc   = (float)((double)g[j] * rstd);
        scale[j] = sc;
        shift[j] = be[j] - (float)(mu * (double)g[j] * rstd);
    }
}

extern "C" void kernel_launch(void* const* d_in, const int* in_sizes, int n_in,
                              void* d_out, int out_size, void* d_ws, size_t ws_size,
                              hipStream_t stream) {
    const float* x = (const float*)d_in[0];
    const int* ei = (const int*)d_in[1];
    const int* src = ei;             // edge_index[0]
    const int* dst = ei + NE;        // edge_index[1]
    const float* W1 = (const float*)d_in[2];  const float* b1 = (const float*)d_in[3];
    const float* W2 = (const float*)d_in[4];  const float* b2 = (const float*)d_in[5];
    const float* W3 = (const float*)d_in[6];  const float* b3 = (const float*)d_in[7];
    const float* W4 = (const float*)d_in[8];  const float* b4 = (const float*)d_in[9];
    const float* W5 = (const float*)d_in[10]; const float* b5 = (const float*)d_in[11];
    const float* W6 = (const float*)d_in[12]; const float* b6 = (const float*)d_in[13];
    const float* g1 = (const float*)d_in[14]; const float* be1 = (const float*)d_in[15];
    const float* g2 = (const float*)d_in[16]; const float* be2 = (const float*)d_in[17];
    const float* g3 = (const float*)d_in[18]; const float* be3 = (const float*)d_in[19];
    const float* g4 = (const float*)d_in[20]; const float* be4 = (const float*)d_in[21];

    // workspace (~35.6 MB)
    float* ws = (float*)d_ws;
    float* dis   = ws;                          // N
    float* h     = dis + NN;                    // N*88
    float* Aa    = h + (size_t)NN * 88;         // N*70 (layers 1,3,5)
    float* bnacc = Aa + (size_t)NN * 70;        // 4 layers * 192
    float* scale = bnacc + 768;                 // 96
    float* shift = scale + 96;                  // 96
    int* deg     = (int*)(shift + 96);          // N
    int* row_ptr = deg + NN;                    // N+1
    int* cursor  = row_ptr + NN + 1;            // N
    int* col     = cursor + NN;                 // E
    float* out   = (float*)d_out;               // layers 2,4 scratch + final

    const int NB = 256;

    // ---- CSR + normalization build ----
    k_prep<<<cdiv(NN, NB), NB, 0, stream>>>(deg, bnacc);
    k_hist<<<cdiv(NE, NB), NB, 0, stream>>>(dst, deg);
    k_scan<<<1, 1024, 0, stream>>>(deg, row_ptr);
    k_dis<<<cdiv(NN, NB), NB, 0, stream>>>(deg, dis);
    k_cursor<<<cdiv(NN, NB), NB, 0, stream>>>(row_ptr, cursor);
    k_fill<<<cdiv(NE, NB), NB, 0, stream>>>(src, dst, cursor, col);

    // ---- L1: x[88] -> 70, relu+bn(g1), A in Aa ----
    k_dense<0><<<NN, 128, 0, stream>>>(x, W1, nullptr, nullptr, h, 88, 70);
    k_gather<70><<<cdiv((long long)NN * 70, NB), NB, 0, stream>>>(h, row_ptr, col, dis, b1, Aa);
    k_bnpart<<<512, NB, 0, stream>>>(Aa, 70, bnacc + 0 * 192);
    k_bnfin<<<1, 96, 0, stream>>>(bnacc + 0 * 192, g1, be1, scale, shift, 70);

    // ---- L2: 70 -> 60, relu+bn(g2), A in out ----
    k_dense<1><<<NN, 128, 0, stream>>>(Aa, W2, scale, shift, h, 70, 60);
    k_gather<60><<<cdiv((long long)NN * 60, NB), NB, 0, stream>>>(h, row_ptr, col, dis, b2, out);
    k_bnpart<<<512, NB, 0, stream>>>(out, 60, bnacc + 1 * 192);
    k_bnfin<<<1, 96, 0, stream>>>(bnacc + 1 * 192, g2, be2, scale, shift, 60);

    // ---- L3: 60 -> 50, no relu/bn, A in Aa ----
    k_dense<1><<<NN, 128, 0, stream>>>(out, W3, scale, shift, h, 60, 50);
    k_gather<50><<<cdiv((long long)NN * 50, NB), NB, 0, stream>>>(h, row_ptr, col, dis, b3, Aa);

    // ---- L4: 50 -> 60 (raw), relu+bn(g3), A in out ----
    k_dense<0><<<NN, 128, 0, stream>>>(Aa, W4, nullptr, nullptr, h, 50, 60);
    k_gather<60><<<cdiv((long long)NN * 60, NB), NB, 0, stream>>>(h, row_ptr, col, dis, b4, out);
    k_bnpart<<<512, NB, 0, stream>>>(out, 60, bnacc + 2 * 192);
    k_bnfin<<<1, 96, 0, stream>>>(bnacc + 2 * 192, g3, be3, scale, shift, 60);

    // ---- L5: 60 -> 70, relu+bn(g4), A in Aa ----
    k_dense<1><<<NN, 128, 0, stream>>>(out, W5, scale, shift, h, 60, 70);
    k_gather<70><<<cdiv((long long)NN * 70, NB), NB, 0, stream>>>(h, row_ptr, col, dis, b5, Aa);
    k_bnpart<<<512, NB, 0, stream>>>(Aa, 70, bnacc + 3 * 192);
    k_bnfin<<<1, 96, 0, stream>>>(bnacc + 3 * 192, g4, be4, scale, shift, 70);

    // ---- L6: 70 -> 88, output ----
    k_dense<1><<<NN, 128, 0, stream>>>(Aa, W6, scale, shift, h, 70, 88);
    k_gather<88><<<cdiv((long long)NN * 88, NB), NB, 0, stream>>>(h, row_ptr, col, dis, b6, out);
}

// Round 4
// 953.429 us; speedup vs baseline: 2.2046x; 1.2479x over previous
//
#include <hip/hip_runtime.h>

#define NN 50000
#define NE 800000

static inline int cdiv(long long a, long long b) { return (int)((a + b - 1) / b); }

// ---------------- CSR build ----------------

__global__ void k_prep(int* __restrict__ deg, float* __restrict__ bnacc) {
    int i = blockIdx.x * blockDim.x + threadIdx.x;
    if (i < NN) deg[i] = 0;
    if (i < 768) bnacc[i] = 0.0f;
}

__global__ void k_hist(const int* __restrict__ dst, int* __restrict__ deg) {
    int e = blockIdx.x * blockDim.x + threadIdx.x;
    if (e < NE) {
        int d = dst[e];
        if ((unsigned)d < NN) atomicAdd(&deg[d], 1);
    }
}

// scan + dis + cursor in one kernel
__global__ __launch_bounds__(1024) void k_scan(const int* __restrict__ deg,
                                               int* __restrict__ row_ptr,
                                               int* __restrict__ cursor,
                                               float* __restrict__ dis) {
    const int T = 1024;
    __shared__ int lds[T];
    int tid = threadIdx.x;
    const int chunk = (NN + T - 1) / T;  // 49
    int lo = tid * chunk;
    int hi = lo + chunk; if (hi > NN) hi = NN;
    int s = 0;
    for (int i = lo; i < hi; ++i) s += deg[i];
    lds[tid] = s;
    __syncthreads();
    int val = s;
    for (int o = 1; o < T; o <<= 1) {
        int v = (tid >= o) ? lds[tid - o] : 0;
        __syncthreads();
        lds[tid] += v;
        __syncthreads();
    }
    int run = lds[tid] - val;  // exclusive prefix
    for (int i = lo; i < hi; ++i) {
        row_ptr[i] = run;
        cursor[i] = run;
        dis[i] = rsqrtf((float)(deg[i] + 1));  // +1 self-loop
        run += deg[i];
    }
    if (tid == T - 1) row_ptr[NN] = lds[T - 1];
}

__global__ void k_fill(const int* __restrict__ src, const int* __restrict__ dst,
                       const float* __restrict__ dis,
                       int* __restrict__ cursor, int* __restrict__ col,
                       float* __restrict__ wgt) {
    int e = blockIdx.x * blockDim.x + threadIdx.x;
    if (e < NE) {
        int s = src[e], d = dst[e];
        if ((unsigned)s < NN && (unsigned)d < NN) {
            int p = atomicAdd(&cursor[d], 1);
            col[p] = s;
            wgt[p] = dis[s] * dis[d];
        }
    }
}

// ---------------- dense: H = in_tf(X) @ W (+ b) ----------------
template<int FI, int FO, int IN_BN, int OUT_BIAS>
__global__ void k_dense(const float* __restrict__ X, const float* __restrict__ W,
                        const float* __restrict__ bnacc, const float* __restrict__ g,
                        const float* __restrict__ be, const float* __restrict__ b,
                        float* __restrict__ H) {
    __shared__ float xs[FI];
    int node = blockIdx.x;
    int tid = threadIdx.x;
    if (tid < FI) {
        float v = X[(size_t)node * FI + tid];
        if (IN_BN) {
            const float inv_n = 1.0f / NN;
            float mu = bnacc[tid] * inv_n;
            float va = bnacc[96 + tid] * inv_n - mu * mu;
            float r  = rsqrtf(va + 1e-5f);
            float sc = g[tid] * r;
            v = fmaxf(v, 0.0f) * sc + (be[tid] - mu * sc);
        }
        xs[tid] = v;
    }
    __syncthreads();
    int j = tid;
    if (j < FO) {
        float acc = OUT_BIAS ? b[j] : 0.0f;
        #pragma unroll 8
        for (int k = 0; k < FI; ++k) acc = fmaf(xs[k], W[k * FO + j], acc);
        H[(size_t)node * FO + j] = acc;
    }
}

// ---------------- CSR gather (float2, unroll-4) ----------------
// A[i,:] = sum_{k in row i} wgt[k] * tf(h[col[k],:]) + dis[i]^2 * tf(h[i,:]) (+ b)
template<int FO, int IN_BN, int OUT_BIAS>
__global__ void k_gather(const float* __restrict__ h, const int* __restrict__ row_ptr,
                         const int* __restrict__ col, const float* __restrict__ wgt,
                         const float* __restrict__ dis,
                         const float* __restrict__ bnacc, const float* __restrict__ g,
                         const float* __restrict__ be,
                         const float* __restrict__ b, float* __restrict__ A) {
    constexpr int F2 = FO / 2;
    int t = blockIdx.x * blockDim.x + threadIdx.x;
    if (t >= NN * F2) return;
    int i = t / F2;
    int j = (t - i * F2) * 2;

    float sc0 = 1.0f, sh0 = 0.0f, sc1 = 1.0f, sh1 = 0.0f;
    if (IN_BN) {
        const float inv_n = 1.0f / NN;
        float mu0 = bnacc[j] * inv_n;
        float va0 = bnacc[96 + j] * inv_n - mu0 * mu0;
        float r0  = rsqrtf(va0 + 1e-5f);
        sc0 = g[j] * r0; sh0 = be[j] - mu0 * sc0;
        float mu1 = bnacc[j + 1] * inv_n;
        float va1 = bnacc[96 + j + 1] * inv_n - mu1 * mu1;
        float r1  = rsqrtf(va1 + 1e-5f);
        sc1 = g[j + 1] * r1; sh1 = be[j + 1] - mu1 * sc1;
    }

    const float* hj = h + j;
    float di = dis[i];

    // self-loop
    float2 hv = *(const float2*)(hj + (size_t)i * FO);
    float vx = IN_BN ? fmaxf(hv.x, 0.0f) * sc0 + sh0 : hv.x;
    float vy = IN_BN ? fmaxf(hv.y, 0.0f) * sc1 + sh1 : hv.y;
    float ax = vx * di * di;
    float ay = vy * di * di;

    int k = row_ptr[i], end = row_ptr[i + 1];
    for (; k + 4 <= end; k += 4) {
        int s0 = col[k], s1 = col[k + 1], s2 = col[k + 2], s3 = col[k + 3];
        float w0 = wgt[k], w1 = wgt[k + 1], w2 = wgt[k + 2], w3 = wgt[k + 3];
        float2 a0 = *(const float2*)(hj + (size_t)s0 * FO);
        float2 a1 = *(const float2*)(hj + (size_t)s1 * FO);
        float2 a2 = *(const float2*)(hj + (size_t)s2 * FO);
        float2 a3 = *(const float2*)(hj + (size_t)s3 * FO);
        if (IN_BN) {
            a0.x = fmaxf(a0.x, 0.0f) * sc0 + sh0; a0.y = fmaxf(a0.y, 0.0f) * sc1 + sh1;
            a1.x = fmaxf(a1.x, 0.0f) * sc0 + sh0; a1.y = fmaxf(a1.y, 0.0f) * sc1 + sh1;
            a2.x = fmaxf(a2.x, 0.0f) * sc0 + sh0; a2.y = fmaxf(a2.y, 0.0f) * sc1 + sh1;
            a3.x = fmaxf(a3.x, 0.0f) * sc0 + sh0; a3.y = fmaxf(a3.y, 0.0f) * sc1 + sh1;
        }
        ax = fmaf(a0.x, w0, ax); ay = fmaf(a0.y, w0, ay);
        ax = fmaf(a1.x, w1, ax); ay = fmaf(a1.y, w1, ay);
        ax = fmaf(a2.x, w2, ax); ay = fmaf(a2.y, w2, ay);
        ax = fmaf(a3.x, w3, ax); ay = fmaf(a3.y, w3, ay);
    }
    for (; k < end; ++k) {
        int s = col[k];
        float w = wgt[k];
        float2 a0 = *(const float2*)(hj + (size_t)s * FO);
        if (IN_BN) {
            a0.x = fmaxf(a0.x, 0.0f) * sc0 + sh0; a0.y = fmaxf(a0.y, 0.0f) * sc1 + sh1;
        }
        ax = fmaf(a0.x, w, ax); ay = fmaf(a0.y, w, ay);
    }
    if (OUT_BIAS) { ax += b[j]; ay += b[j + 1]; }
    float2 res = make_float2(ax, ay);
    *(float2*)(A + (size_t)i * FO + j) = res;
}

// ---------------- BN partial sums over relu(A) ----------------
// grid must satisfy (gridDim*blockDim) % (FO/2) == 0 so each thread owns fixed j
template<int FO>
__global__ void k_bnpart(const float* __restrict__ A, float* __restrict__ acc) {
    constexpr int F2 = FO / 2;
    __shared__ float ls[96], lq[96];
    int tid = threadIdx.x;
    if (tid < 96) { ls[tid] = 0.0f; lq[tid] = 0.0f; }
    __syncthreads();
    const float2* A2 = (const float2*)A;
    int t2 = blockIdx.x * blockDim.x + tid;
    int j2 = t2 % F2;          // constant across iterations (stride % F2 == 0)
    int stride = gridDim.x * blockDim.x;
    float sx = 0.0f, qx = 0.0f, sy = 0.0f, qy = 0.0f;
    for (; t2 < NN * F2; t2 += stride) {
        float2 v = A2[t2];
        float x = fmaxf(v.x, 0.0f), y = fmaxf(v.y, 0.0f);
        sx += x; qx += x * x;
        sy += y; qy += y * y;
    }
    atomicAdd(&ls[2 * j2], sx);     atomicAdd(&ls[2 * j2 + 1], sy);
    atomicAdd(&lq[2 * j2], qx);     atomicAdd(&lq[2 * j2 + 1], qy);
    __syncthreads();
    if (tid < FO) {
        atomicAdd(&acc[tid], ls[tid]);
        atomicAdd(&acc[96 + tid], lq[tid]);
    }
}

extern "C" void kernel_launch(void* const* d_in, const int* in_sizes, int n_in,
                              void* d_out, int out_size, void* d_ws, size_t ws_size,
                              hipStream_t stream) {
    const float* x = (const float*)d_in[0];
    const int* ei = (const int*)d_in[1];
    const int* src = ei;             // edge_index[0]
    const int* dst = ei + NE;        // edge_index[1]
    const float* W1 = (const float*)d_in[2];  const float* b1 = (const float*)d_in[3];
    const float* W2 = (const float*)d_in[4];  const float* b2 = (const float*)d_in[5];
    const float* W3 = (const float*)d_in[6];  const float* b3 = (const float*)d_in[7];
    const float* W4 = (const float*)d_in[8];  const float* b4 = (const float*)d_in[9];
    const float* W5 = (const float*)d_in[10]; const float* b5 = (const float*)d_in[11];
    const float* W6 = (const float*)d_in[12]; const float* b6 = (const float*)d_in[13];
    const float* g1 = (const float*)d_in[14]; const float* be1 = (const float*)d_in[15];
    const float* g2 = (const float*)d_in[16]; const float* be2 = (const float*)d_in[17];
    const float* g3 = (const float*)d_in[18]; const float* be3 = (const float*)d_in[19];
    const float* g4 = (const float*)d_in[20]; const float* be4 = (const float*)d_in[21];

    // workspace (~35.2 MB)
    float* ws = (float*)d_ws;
    float* dis   = ws;                          // NN
    float* h     = dis + NN;                    // NN*70
    float* Aa    = h + (size_t)NN * 70;         // NN*70
    float* bnacc = Aa + (size_t)NN * 70;        // 4*192
    int* deg     = (int*)(bnacc + 768);         // NN
    int* row_ptr = deg + NN;                    // NN+1
    int* cursor  = row_ptr + NN + 1;            // NN
    int* col     = cursor + NN;                 // NE
    float* wgt   = (float*)(col + NE);          // NE
    float* out   = (float*)d_out;               // scratch (A2, A4) + final

    const int NB = 256;
    float* bn0 = bnacc;        // L1 stats (g1)
    float* bn1 = bnacc + 192;  // L2 stats (g2)
    float* bn2 = bnacc + 384;  // L4 stats (g3)
    float* bn3 = bnacc + 576;  // L5 stats (g4)

    // ---- CSR + normalization build ----
    k_prep<<<cdiv(NN, NB), NB, 0, stream>>>(deg, bnacc);
    k_hist<<<cdiv(NE, NB), NB, 0, stream>>>(dst, deg);
    k_scan<<<1, 1024, 0, stream>>>(deg, row_ptr, cursor, dis);
    k_fill<<<cdiv(NE, NB), NB, 0, stream>>>(src, dst, dis, cursor, col, wgt);

    // ---- L1: dense x(88)->h(70); gather h -> A1(Aa) + b1; stats ----
    k_dense<88, 70, 0, 0><<<NN, 128, 0, stream>>>(x, W1, nullptr, nullptr, nullptr, nullptr, h);
    k_gather<70, 0, 1><<<cdiv((long long)NN * 35, NB), NB, 0, stream>>>(
        h, row_ptr, col, wgt, dis, nullptr, nullptr, nullptr, b1, Aa);
    k_bnpart<70><<<35 * 56, NB, 0, stream>>>(Aa, bn0);

    // ---- L2: dense A1(bn) -> h(60); gather h -> A2(out) + b2; stats ----
    k_dense<70, 60, 1, 0><<<NN, 128, 0, stream>>>(Aa, W2, bn0, g1, be1, nullptr, h);
    k_gather<60, 0, 1><<<cdiv((long long)NN * 30, NB), NB, 0, stream>>>(
        h, row_ptr, col, wgt, dis, nullptr, nullptr, nullptr, b2, out);
    k_bnpart<60><<<30 * 56, NB, 0, stream>>>(out, bn1);

    // ---- L3: dense A2(bn) -> h(50); gather h -> A3(Aa) + b3 ----
    k_dense<60, 50, 1, 0><<<NN, 128, 0, stream>>>(out, W3, bn1, g2, be2, nullptr, h);
    k_gather<50, 0, 1><<<cdiv((long long)NN * 25, NB), NB, 0, stream>>>(
        h, row_ptr, col, wgt, dis, nullptr, nullptr, nullptr, b3, Aa);

    // ---- L4 (aggregate-first): gather A3 -> agg4(h,50); dense h -> A4(out,60)+b4; stats ----
    k_gather<50, 0, 0><<<cdiv((long long)NN * 25, NB), NB, 0, stream>>>(
        Aa, row_ptr, col, wgt, dis, nullptr, nullptr, nullptr, nullptr, h);
    k_dense<50, 60, 0, 1><<<NN, 128, 0, stream>>>(h, W4, nullptr, nullptr, nullptr, b4, out);
    k_bnpart<60><<<30 * 56, NB, 0, stream>>>(out, bn2);

    // ---- L5: gather bn(relu(A4)) -> agg5(h,60); dense h -> A5(Aa,70)+b5; stats ----
    k_gather<60, 1, 0><<<cdiv((long long)NN * 30, NB), NB, 0, stream>>>(
        out, row_ptr, col, wgt, dis, bn2, g3, be3, nullptr, h);
    k_dense<60, 70, 0, 1><<<NN, 128, 0, stream>>>(h, W5, nullptr, nullptr, nullptr, b5, Aa);
    k_bnpart<70><<<35 * 56, NB, 0, stream>>>(Aa, bn3);

    // ---- L6: gather bn(relu(A5)) -> agg6(h,70); dense h -> out(88)+b6 ----
    k_gather<70, 1, 0><<<cdiv((long long)NN * 35, NB), NB, 0, stream>>>(
        Aa, row_ptr, col, wgt, dis, bn3, g4, be4, nullptr, h);
    k_dense<70, 88, 0, 1><<<NN, 128, 0, stream>>>(h, W6, nullptr, nullptr, nullptr, b6, out);
}

// Round 5
// 767.963 us; speedup vs baseline: 2.7370x; 1.2415x over previous
//
#include <hip/hip_runtime.h>
#include <hip/hip_bf16.h>

typedef unsigned int  uint_t;
typedef unsigned short ushort_t;

#define NN 50000
#define NE 800000
#define NBLK 196  // cdiv(NN,256)

static inline int cdiv(long long a, long long b) { return (int)((a + b - 1) / b); }

// ---- bf16 pair helpers (element j at low 16 bits) ----
__device__ inline float bflo(uint_t u) { return __uint_as_float(u << 16); }
__device__ inline float bfhi(uint_t u) { return __uint_as_float(u & 0xffff0000u); }
__device__ inline uint_t packbf(float x, float y) {  // RNE
    uint_t xu = __float_as_uint(x), yu = __float_as_uint(y);
    xu += 0x7fffu + ((xu >> 16) & 1u);
    yu += 0x7fffu + ((yu >> 16) & 1u);
    return (xu >> 16) | (yu & 0xffff0000u);
}
__device__ inline float bf1(ushort_t u) { return __uint_as_float(((uint_t)u) << 16); }
__device__ inline ushort_t packbf1(float x) {
    uint_t xu = __float_as_uint(x);
    xu += 0x7fffu + ((xu >> 16) & 1u);
    return (ushort_t)(xu >> 16);
}

// ---------------- CSR build ----------------

__global__ void k_prep(int* __restrict__ deg, float* __restrict__ bnacc) {
    int i = blockIdx.x * blockDim.x + threadIdx.x;
    if (i < NN) deg[i] = 0;
    if (i < 768) bnacc[i] = 0.0f;
}

__global__ void k_hist(const int* __restrict__ dst, int* __restrict__ deg) {
    int e = blockIdx.x * blockDim.x + threadIdx.x;
    if (e < NE) {
        int d = dst[e];
        if ((unsigned)d < NN) atomicAdd(&deg[d], 1);
    }
}

__global__ void k_bsum(const int* __restrict__ deg, int* __restrict__ bsum) {
    __shared__ int l[256];
    int tid = threadIdx.x;
    int i = blockIdx.x * 256 + tid;
    l[tid] = (i < NN) ? deg[i] : 0;
    __syncthreads();
    for (int o = 128; o > 0; o >>= 1) {
        if (tid < o) l[tid] += l[tid + o];
        __syncthreads();
    }
    if (tid == 0) bsum[blockIdx.x] = l[0];
}

__global__ void k_bscan(const int* __restrict__ bsum, int* __restrict__ boff,
                        int* __restrict__ row_ptr) {
    __shared__ int l[256];
    int tid = threadIdx.x;
    int v = (tid < NBLK) ? bsum[tid] : 0;
    l[tid] = v;
    __syncthreads();
    for (int o = 1; o < 256; o <<= 1) {
        int t = (tid >= o) ? l[tid - o] : 0;
        __syncthreads();
        l[tid] += t;
        __syncthreads();
    }
    boff[tid] = l[tid] - v;            // exclusive block offset
    if (tid == 255) row_ptr[NN] = l[255];  // total
}

__global__ void k_rowptr(const int* __restrict__ deg, const int* __restrict__ boff,
                         int* __restrict__ row_ptr, int* __restrict__ cursor,
                         float* __restrict__ dis) {
    __shared__ int l[256];
    int tid = threadIdx.x;
    int i = blockIdx.x * 256 + tid;
    int v = (i < NN) ? deg[i] : 0;
    l[tid] = v;
    __syncthreads();
    for (int o = 1; o < 256; o <<= 1) {
        int t = (tid >= o) ? l[tid - o] : 0;
        __syncthreads();
        l[tid] += t;
        __syncthreads();
    }
    if (i < NN) {
        int excl = boff[blockIdx.x] + l[tid] - v;
        row_ptr[i] = excl;
        cursor[i] = excl;
        dis[i] = rsqrtf((float)(v + 1));  // +1 self-loop
    }
}

__global__ void k_fill(const int* __restrict__ src, const int* __restrict__ dst,
                       const float* __restrict__ dis,
                       int* __restrict__ cursor, int* __restrict__ col,
                       float* __restrict__ wgt) {
    int e = blockIdx.x * blockDim.x + threadIdx.x;
    if (e < NE) {
        int s = src[e], d = dst[e];
        if ((unsigned)s < NN && (unsigned)d < NN) {
            int p = atomicAdd(&cursor[d], 1);
            col[p] = s;
            wgt[p] = dis[s] * dis[d];
        }
    }
}

// ---------------- dense: H = in_tf(X) @ W (+ b) ----------------
// IN_F32: X is fp32 (layer 1) else bf16. OUT_F32: H fp32 (final) else bf16.
template<int FI, int FO, int IN_BN, int OUT_BIAS, int IN_F32, int OUT_F32>
__global__ void k_dense(const void* __restrict__ Xv, const float* __restrict__ W,
                        const float* __restrict__ bnacc, const float* __restrict__ g,
                        const float* __restrict__ be, const float* __restrict__ b,
                        void* __restrict__ Hv) {
    __shared__ float xs[FI];
    int node = blockIdx.x;
    int tid = threadIdx.x;
    if (tid < FI) {
        float v;
        if (IN_F32) v = ((const float*)Xv)[(size_t)node * FI + tid];
        else        v = bf1(((const ushort_t*)Xv)[(size_t)node * FI + tid]);
        if (IN_BN) {
            const float inv_n = 1.0f / NN;
            float mu = bnacc[tid] * inv_n;
            float va = bnacc[96 + tid] * inv_n - mu * mu;
            float r  = rsqrtf(va + 1e-5f);
            float sc = g[tid] * r;
            v = fmaxf(v, 0.0f) * sc + (be[tid] - mu * sc);
        }
        xs[tid] = v;
    }
    __syncthreads();
    int j = tid;
    if (j < FO) {
        float acc = OUT_BIAS ? b[j] : 0.0f;
        #pragma unroll 8
        for (int k = 0; k < FI; ++k) acc = fmaf(xs[k], W[k * FO + j], acc);
        if (OUT_F32) ((float*)Hv)[(size_t)node * FO + j] = acc;
        else         ((ushort_t*)Hv)[(size_t)node * FO + j] = packbf1(acc);
    }
}

// ---------------- CSR gather (bf16 in/out, unroll-8) ----------------
// A[i,:] = sum_k wgt[k]*tf(h[col[k],:]) + dis[i]^2*tf(h[i,:]) (+ b)
template<int FO, int IN_BN, int OUT_BIAS>
__global__ void k_gather(const ushort_t* __restrict__ h, const int* __restrict__ row_ptr,
                         const int* __restrict__ col, const float* __restrict__ wgt,
                         const float* __restrict__ dis,
                         const float* __restrict__ bnacc, const float* __restrict__ g,
                         const float* __restrict__ be,
                         const float* __restrict__ b, ushort_t* __restrict__ A) {
    constexpr int F2 = FO / 2;
    int t = blockIdx.x * blockDim.x + threadIdx.x;
    if (t >= NN * F2) return;
    int i = t / F2;
    int j2 = t - i * F2;
    int j = 2 * j2;

    float sc0 = 1.0f, sh0 = 0.0f, sc1 = 1.0f, sh1 = 0.0f;
    if (IN_BN) {
        const float inv_n = 1.0f / NN;
        float mu0 = bnacc[j] * inv_n;
        float va0 = bnacc[96 + j] * inv_n - mu0 * mu0;
        float r0  = rsqrtf(va0 + 1e-5f);
        sc0 = g[j] * r0; sh0 = be[j] - mu0 * sc0;
        float mu1 = bnacc[j + 1] * inv_n;
        float va1 = bnacc[96 + j + 1] * inv_n - mu1 * mu1;
        float r1  = rsqrtf(va1 + 1e-5f);
        sc1 = g[j + 1] * r1; sh1 = be[j + 1] - mu1 * sc1;
    }

    const uint_t* h2 = (const uint_t*)h + j2;  // column pair j within rows
    float di = dis[i];

    // self-loop
    uint_t su = h2[(size_t)i * F2];
    float vx = bflo(su), vy = bfhi(su);
    if (IN_BN) { vx = fmaxf(vx, 0.0f) * sc0 + sh0; vy = fmaxf(vy, 0.0f) * sc1 + sh1; }
    float ax = vx * di * di;
    float ay = vy * di * di;

    int k = row_ptr[i], end = row_ptr[i + 1];
    for (; k + 8 <= end; k += 8) {
        uint_t uu[8]; float ww[8];
        #pragma unroll
        for (int q = 0; q < 8; ++q) {
            int s = col[k + q];
            ww[q] = wgt[k + q];
            uu[q] = h2[(size_t)s * F2];
        }
        #pragma unroll
        for (int q = 0; q < 8; ++q) {
            float tx = bflo(uu[q]), ty = bfhi(uu[q]);
            if (IN_BN) { tx = fmaxf(tx, 0.0f) * sc0 + sh0; ty = fmaxf(ty, 0.0f) * sc1 + sh1; }
            ax = fmaf(tx, ww[q], ax); ay = fmaf(ty, ww[q], ay);
        }
    }
    for (; k < end; ++k) {
        int s = col[k];
        float w = wgt[k];
        uint_t u = h2[(size_t)s * F2];
        float tx = bflo(u), ty = bfhi(u);
        if (IN_BN) { tx = fmaxf(tx, 0.0f) * sc0 + sh0; ty = fmaxf(ty, 0.0f) * sc1 + sh1; }
        ax = fmaf(tx, w, ax); ay = fmaf(ty, w, ay);
    }
    if (OUT_BIAS) { ax += b[j]; ay += b[j + 1]; }
    ((uint_t*)A)[(size_t)i * F2 + j2] = packbf(ax, ay);
}

// ---------------- BN partial sums over relu(A), bf16 input ----------------
// grid*block stride is a multiple of F2 so each thread owns a fixed feature pair
template<int FO>
__global__ void k_bnpart(const ushort_t* __restrict__ A, float* __restrict__ acc) {
    constexpr int F2 = FO / 2;
    __shared__ float ls[96], lq[96];
    int tid = threadIdx.x;
    if (tid < 96) { ls[tid] = 0.0f; lq[tid] = 0.0f; }
    __syncthreads();
    const uint_t* A2 = (const uint_t*)A;
    int t2 = blockIdx.x * blockDim.x + tid;
    int j2 = t2 % F2;
    int stride = gridDim.x * blockDim.x;
    float sx = 0.0f, qx = 0.0f, sy = 0.0f, qy = 0.0f;
    for (; t2 < NN * F2; t2 += stride) {
        uint_t u = A2[t2];
        float x = fmaxf(bflo(u), 0.0f), y = fmaxf(bfhi(u), 0.0f);
        sx += x; qx += x * x;
        sy += y; qy += y * y;
    }
    atomicAdd(&ls[2 * j2], sx);     atomicAdd(&ls[2 * j2 + 1], sy);
    atomicAdd(&lq[2 * j2], qx);     atomicAdd(&lq[2 * j2 + 1], qy);
    __syncthreads();
    if (tid < FO) {
        atomicAdd(&acc[tid], ls[tid]);
        atomicAdd(&acc[96 + tid], lq[tid]);
    }
}

extern "C" void kernel_launch(void* const* d_in, const int* in_sizes, int n_in,
                              void* d_out, int out_size, void* d_ws, size_t ws_size,
                              hipStream_t stream) {
    const float* x = (const float*)d_in[0];
    const int* ei = (const int*)d_in[1];
    const int* src = ei;             // edge_index[0]
    const int* dst = ei + NE;        // edge_index[1]
    const float* W1 = (const float*)d_in[2];  const float* b1 = (const float*)d_in[3];
    const float* W2 = (const float*)d_in[4];  const float* b2 = (const float*)d_in[5];
    const float* W3 = (const float*)d_in[6];  const float* b3 = (const float*)d_in[7];
    const float* W4 = (const float*)d_in[8];  const float* b4 = (const float*)d_in[9];
    const float* W5 = (const float*)d_in[10]; const float* b5 = (const float*)d_in[11];
    const float* W6 = (const float*)d_in[12]; const float* b6 = (const float*)d_in[13];
    const float* g1 = (const float*)d_in[14]; const float* be1 = (const float*)d_in[15];
    const float* g2 = (const float*)d_in[16]; const float* be2 = (const float*)d_in[17];
    const float* g3 = (const float*)d_in[18]; const float* be3 = (const float*)d_in[19];
    const float* g4 = (const float*)d_in[20]; const float* be4 = (const float*)d_in[21];

    // workspace (~21.5 MB)
    float* ws = (float*)d_ws;
    float* dis    = ws;                         // NN
    float* bnacc  = dis + NN;                   // 768
    float* wgt    = bnacc + 768;                // NE
    int* deg      = (int*)(wgt + NE);           // NN
    int* row_ptr  = deg + NN;                   // NN+1
    int* cursor   = row_ptr + NN + 1;           // NN
    int* col      = cursor + NN;                // NE
    int* bsum     = col + NE;                   // 256
    int* boff     = bsum + 256;                 // 256
    ushort_t* hB  = (ushort_t*)(boff + 256);    // NN*70 bf16
    ushort_t* aB  = hB + (size_t)NN * 70;       // NN*70 bf16
    float* out    = (float*)d_out;

    const int NB = 256;
    float* bn0 = bnacc;        // L1 stats (g1,be1)
    float* bn1 = bnacc + 192;  // L2 stats (g2,be2)
    float* bn2 = bnacc + 384;  // L4 stats (g3,be3)
    float* bn3 = bnacc + 576;  // L5 stats (g4,be4)

    // ---- CSR + normalization build ----
    k_prep<<<cdiv(NN, NB), NB, 0, stream>>>(deg, bnacc);
    k_hist<<<cdiv(NE, NB), NB, 0, stream>>>(dst, deg);
    k_bsum<<<NBLK, 256, 0, stream>>>(deg, bsum);
    k_bscan<<<1, 256, 0, stream>>>(bsum, boff, row_ptr);
    k_rowptr<<<NBLK, 256, 0, stream>>>(deg, boff, row_ptr, cursor, dis);
    k_fill<<<cdiv(NE, NB), NB, 0, stream>>>(src, dst, dis, cursor, col, wgt);

    // ---- L1: dense x(88,f32)->hB(70); gather hB -> aB + b1; stats bn0 ----
    k_dense<88, 70, 0, 0, 1, 0><<<NN, 128, 0, stream>>>(x, W1, nullptr, nullptr, nullptr, nullptr, hB);
    k_gather<70, 0, 1><<<cdiv((long long)NN * 35, NB), NB, 0, stream>>>(
        hB, row_ptr, col, wgt, dis, nullptr, nullptr, nullptr, b1, aB);
    k_bnpart<70><<<35 * 56, NB, 0, stream>>>(aB, bn0);

    // ---- L2: dense bn(aB)(70)->hB(60); gather hB -> aB + b2; stats bn1 ----
    k_dense<70, 60, 1, 0, 0, 0><<<NN, 128, 0, stream>>>(aB, W2, bn0, g1, be1, nullptr, hB);
    k_gather<60, 0, 1><<<cdiv((long long)NN * 30, NB), NB, 0, stream>>>(
        hB, row_ptr, col, wgt, dis, nullptr, nullptr, nullptr, b2, aB);
    k_bnpart<60><<<30 * 56, NB, 0, stream>>>(aB, bn1);

    // ---- L3: dense bn(aB)(60)->hB(50); gather hB -> aB + b3 (A3) ----
    k_dense<60, 50, 1, 0, 0, 0><<<NN, 128, 0, stream>>>(aB, W3, bn1, g2, be2, nullptr, hB);
    k_gather<50, 0, 1><<<cdiv((long long)NN * 25, NB), NB, 0, stream>>>(
        hB, row_ptr, col, wgt, dis, nullptr, nullptr, nullptr, b3, aB);

    // ---- L4 (aggregate-first): gather aB(A3) -> hB(agg4,50); dense hB -> aB(A4,60)+b4; stats bn2 ----
    k_gather<50, 0, 0><<<cdiv((long long)NN * 25, NB), NB, 0, stream>>>(
        aB, row_ptr, col, wgt, dis, nullptr, nullptr, nullptr, nullptr, hB);
    k_dense<50, 60, 0, 1, 0, 0><<<NN, 128, 0, stream>>>(hB, W4, nullptr, nullptr, nullptr, b4, aB);
    k_bnpart<60><<<30 * 56, NB, 0, stream>>>(aB, bn2);

    // ---- L5: gather bn(aB=A4) -> hB(agg5,60); dense hB -> aB(A5,70)+b5; stats bn3 ----
    k_gather<60, 1, 0><<<cdiv((long long)NN * 30, NB), NB, 0, stream>>>(
        aB, row_ptr, col, wgt, dis, bn2, g3, be3, nullptr, hB);
    k_dense<60, 70, 0, 1, 0, 0><<<NN, 128, 0, stream>>>(hB, W5, nullptr, nullptr, nullptr, b5, aB);
    k_bnpart<70><<<35 * 56, NB, 0, stream>>>(aB, bn3);

    // ---- L6: gather bn(aB=A5) -> hB(agg6,70); dense hB -> out(88,f32)+b6 ----
    k_gather<70, 1, 0><<<cdiv((long long)NN * 35, NB), NB, 0, stream>>>(
        aB, row_ptr, col, wgt, dis, bn3, g4, be4, nullptr, hB);
    k_dense<70, 88, 0, 1, 0, 1><<<NN, 128, 0, stream>>>(hB, W6, nullptr, nullptr, nullptr, b6, out);
}